// Round 10
// baseline (118.696 us; speedup 1.0000x reference)
//
#include <hip/hip_runtime.h>

// IDWT2D db4, periodized. Input x: [64][256][256][16] f32 (cA|cH|cV|cD x 4ch),
// output: [64][512][512][4] f32.
//
// R9: R8 + halved pass2 LDS traffic. Pass2 thread = (jx, output-row-parity):
// t&255 -> jx, t>>8 -> p. Each thread reads only its p-plane of the
// intermediate (8 ds_read_b128 per j-row: 4 shifts x {lo,hi}) and computes
// BOTH column parities q -> 4 reads per output f4 (R8: 8). Stores 2 adjacent
// f4 (32B/lane; half-line per instr, pairs merge in L2 - R3 evidence:
// WRITE_SIZE stayed 262144). Pass2 FMA count also halves.
// Rest identical to R8: 1-j-row chunks, 32 KB double-buffered LDS,
// 4 blocks/CU, register sliding window pass1, 1 sync per j-row.

#define N 256
#define RJ 16

__device__ __forceinline__ void fma4(float4& d, float s, const float4 a) {
  d.x = fmaf(s, a.x, d.x);
  d.y = fmaf(s, a.y, d.y);
  d.z = fmaf(s, a.z, d.z);
  d.w = fmaf(s, a.w, d.w);
}

__global__ __launch_bounds__(512, 4) void idwt2_sep9_kernel(
    const float* __restrict__ x, float* __restrict__ out) {
  constexpr float LO[8] = {
      0.23037781330885523f,  0.7148465705525415f,  0.6308807679295904f,
      -0.02798376941698385f, -0.18703481171888114f, 0.030841381835986965f,
      0.032883011666982945f, -0.010597401784997278f};
  constexpr float HIW[8] = {
      -0.010597401784997278f, -0.032883011666982945f, 0.030841381835986965f,
      0.18703481171888114f,  -0.02798376941698385f,  -0.6308807679295904f,
      0.7148465705525415f,   -0.23037781330885523f};
  const float Lw[2][4] = {{LO[6], LO[4], LO[2], LO[0]},
                          {LO[7], LO[5], LO[3], LO[1]}};
  const float Hw[2][4] = {{HIW[6], HIW[4], HIW[2], HIW[0]},
                          {HIW[7], HIW[5], HIW[3], HIW[1]}};

  // [buf][parity p][lo/hi][col] float4 = 32 KB
  __shared__ float4 I[2][2][2][N];

  const int t = threadIdx.x;
  const int bx = blockIdx.x;
  const int b = bx >> 4;           // 16 consecutive blocks per batch
  const int r0 = (bx & 15) * RJ;

  const float4* xb = reinterpret_cast<const float4*>(x) + (size_t)b * N * N * 4;
  float4* ob = reinterpret_cast<float4*>(out) + (size_t)b * (2 * N) * (2 * N);

  // ---- Pass1 identity: column + lo/hi half ----
  const int tcol = t & (N - 1);
  const int thalf = t >> 8;  // 0: lo from (cA,cH); 1: hi from (cV,cD)
  const float4* xcolp = xb + (size_t)tcol * 4 + thalf * 2;

  float4 wA[4], wB[4], nA, nB;
  auto ldrow = [&](int lr, float4& A, float4& B) {
    const int gr = (r0 + lr) & (N - 1);
    A = xcolp[(size_t)gr * (N * 4)];
    B = xcolp[(size_t)gr * (N * 4) + 1];
  };

  // y-filter local j-row j into I[buf]; window slot (j+sy)&3 holds row j+sy.
  auto p1 = [&](int j, int buf) {
    float4 v0 = make_float4(0.f, 0.f, 0.f, 0.f);
    float4 v1 = make_float4(0.f, 0.f, 0.f, 0.f);
#pragma unroll
    for (int sy = 0; sy < 4; ++sy) {
      const float4 a = wA[(j + sy) & 3];
      const float4 bb = wB[(j + sy) & 3];
      fma4(v0, Lw[0][sy], a);
      fma4(v0, Hw[0][sy], bb);
      fma4(v1, Lw[1][sy], a);
      fma4(v1, Hw[1][sy], bb);
    }
    I[buf][0][thalf][tcol] = v0;
    I[buf][1][thalf][tcol] = v1;
  };

  // Prologue: window rows 0..3, prefetch row 4; p1(0) -> I[0].
#pragma unroll
  for (int m = 0; m < 4; ++m) ldrow(m, wA[m], wB[m]);
  ldrow(4, nA, nB);
  p1(0, 0);
  wA[0] = nA;  // row 4 -> slot 0 (row 0 dead)
  wB[0] = nB;
  ldrow(5, nA, nB);
  __syncthreads();

  // ---- Pass2 identity: jx + output-row parity (dense paired stores) ----
  const int jx = t & (N - 1);
  const int phalf = t >> 8;  // which output row parity this thread produces

#pragma unroll
  for (int c = 0; c < RJ; ++c) {
    const int buf = c & 1;

    // ---- Pass2: x-filter j-row c, parity phalf, both column parities ----
    float4 oq0 = make_float4(0.f, 0.f, 0.f, 0.f);
    float4 oq1 = make_float4(0.f, 0.f, 0.f, 0.f);
#pragma unroll
    for (int s = 0; s < 4; ++s) {
      const int xc = (jx + s) & (N - 1);
      const float4 l = I[buf][phalf][0][xc];
      const float4 h = I[buf][phalf][1][xc];
      fma4(oq0, Lw[0][s], l);
      fma4(oq0, Hw[0][s], h);
      fma4(oq1, Lw[1][s], l);
      fma4(oq1, Hw[1][s], h);
    }
    const int jy = r0 + c;
    float4* po = ob + (size_t)(2 * jy + phalf) * (2 * N) + 2 * jx;
    po[0] = oq0;
    po[1] = oq1;

    if (c < RJ - 1) {
      // ---- Pass1: j-row c+1 (uses window rows c+1..c+4) ----
      p1(c + 1, buf ^ 1);
      // Slide: row c+5 (prefetched) -> slot (c+1)&3; prefetch row c+6.
      if (c <= RJ - 3) {
        wA[(c + 1) & 3] = nA;
        wB[(c + 1) & 3] = nB;
      }
      if (c <= RJ - 4) ldrow(c + 6, nA, nB);
      __syncthreads();
    }
  }
}

extern "C" void kernel_launch(void* const* d_in, const int* in_sizes, int n_in,
                              void* d_out, int out_size, void* d_ws,
                              size_t ws_size, hipStream_t stream) {
  const float* x = reinterpret_cast<const float*>(d_in[0]);
  float* out = reinterpret_cast<float*>(d_out);
  const int grid = 64 * (N / RJ);  // 1024 blocks = 4 per CU
  idwt2_sep9_kernel<<<grid, 512, 0, stream>>>(x, out);
}

// Round 11
// 110.201 us; speedup vs baseline: 1.0771x; 1.0771x over previous
//
#include <hip/hip_runtime.h>

// IDWT2D db4, periodized. Input x: [64][256][256][16] f32 (cA|cH|cV|cD x 4ch),
// output: [64][512][512][4] f32.
//
// R10: R8 (best, 110.3 us) with one change: custom barrier that waits only
// lgkmcnt(0) (LDS writes visible) + s_barrier, instead of __syncthreads()
// which drains vmcnt(0) too and kills the cross-barrier global prefetch
// (compiler emits "s_waitcnt vmcnt(0) lgkmcnt(0)" before s_barrier - the
// m97 barrier-drain stall). Prefetched window rows now stay in flight
// across the 15 inner barriers; their latency is covered by a full chunk
// (pass2 + pass1) before the register-copy consumption point.
// Structure: 1-j-row chunks, 32 KB double-buffered LDS, 4 blocks/CU,
// register sliding window pass1 (global reads, row read once/block),
// pass2 thread = output column (dense coalesced f4 stores).

#define N 256
#define RJ 16

// lgkm-only barrier: LDS producer-consumer sync without vmcnt drain.
#define LGKM_BARRIER()                                   \
  do {                                                   \
    asm volatile("s_waitcnt lgkmcnt(0)" ::: "memory");   \
    __builtin_amdgcn_s_barrier();                        \
    asm volatile("" ::: "memory");                       \
  } while (0)

__device__ __forceinline__ void fma4(float4& d, float s, const float4 a) {
  d.x = fmaf(s, a.x, d.x);
  d.y = fmaf(s, a.y, d.y);
  d.z = fmaf(s, a.z, d.z);
  d.w = fmaf(s, a.w, d.w);
}

__global__ __launch_bounds__(512, 4) void idwt2_sep10_kernel(
    const float* __restrict__ x, float* __restrict__ out) {
  constexpr float LO[8] = {
      0.23037781330885523f,  0.7148465705525415f,  0.6308807679295904f,
      -0.02798376941698385f, -0.18703481171888114f, 0.030841381835986965f,
      0.032883011666982945f, -0.010597401784997278f};
  constexpr float HIW[8] = {
      -0.010597401784997278f, -0.032883011666982945f, 0.030841381835986965f,
      0.18703481171888114f,  -0.02798376941698385f,  -0.6308807679295904f,
      0.7148465705525415f,   -0.23037781330885523f};
  const float Lw[2][4] = {{LO[6], LO[4], LO[2], LO[0]},
                          {LO[7], LO[5], LO[3], LO[1]}};
  const float Hw[2][4] = {{HIW[6], HIW[4], HIW[2], HIW[0]},
                          {HIW[7], HIW[5], HIW[3], HIW[1]}};

  // [buf][parity p][lo/hi][col] float4 = 32 KB
  __shared__ float4 I[2][2][2][N];

  const int t = threadIdx.x;
  const int bx = blockIdx.x;
  const int b = bx >> 4;           // 16 consecutive blocks per batch
  const int r0 = (bx & 15) * RJ;

  const float4* xb = reinterpret_cast<const float4*>(x) + (size_t)b * N * N * 4;
  float4* ob = reinterpret_cast<float4*>(out) + (size_t)b * (2 * N) * (2 * N);

  // ---- Pass1 identity: column + lo/hi half ----
  const int tcol = t & (N - 1);
  const int thalf = t >> 8;  // 0: lo from (cA,cH); 1: hi from (cV,cD)
  const float4* xcolp = xb + (size_t)tcol * 4 + thalf * 2;

  float4 wA[4], wB[4], nA, nB;
  auto ldrow = [&](int lr, float4& A, float4& B) {
    const int gr = (r0 + lr) & (N - 1);
    A = xcolp[(size_t)gr * (N * 4)];
    B = xcolp[(size_t)gr * (N * 4) + 1];
  };

  // y-filter local j-row j into I[buf]; window slot (j+sy)&3 holds row j+sy.
  auto p1 = [&](int j, int buf) {
    float4 v0 = make_float4(0.f, 0.f, 0.f, 0.f);
    float4 v1 = make_float4(0.f, 0.f, 0.f, 0.f);
#pragma unroll
    for (int sy = 0; sy < 4; ++sy) {
      const float4 a = wA[(j + sy) & 3];
      const float4 bb = wB[(j + sy) & 3];
      fma4(v0, Lw[0][sy], a);
      fma4(v0, Hw[0][sy], bb);
      fma4(v1, Lw[1][sy], a);
      fma4(v1, Hw[1][sy], bb);
    }
    I[buf][0][thalf][tcol] = v0;
    I[buf][1][thalf][tcol] = v1;
  };

  // Prologue: window rows 0..3, prefetch row 4; p1(0) -> I[0].
#pragma unroll
  for (int m = 0; m < 4; ++m) ldrow(m, wA[m], wB[m]);
  ldrow(4, nA, nB);
  p1(0, 0);
  wA[0] = nA;  // row 4 -> slot 0 (row 0 dead)
  wB[0] = nB;
  ldrow(5, nA, nB);
  LGKM_BARRIER();

  // ---- Pass2 identity: output column t (dense stores) ----
  const int jx = t >> 1;
  const int q = t & 1;
  float Lq[4], Hq[4];
#pragma unroll
  for (int s = 0; s < 4; ++s) {
    Lq[s] = q ? Lw[1][s] : Lw[0][s];
    Hq[s] = q ? Hw[1][s] : Hw[0][s];
  }

#pragma unroll
  for (int c = 0; c < RJ; ++c) {
    const int buf = c & 1;

    // ---- Pass2: x-filter j-row c from I[buf] ----
    float4 o0 = make_float4(0.f, 0.f, 0.f, 0.f);
    float4 o1 = make_float4(0.f, 0.f, 0.f, 0.f);
#pragma unroll
    for (int s = 0; s < 4; ++s) {
      const int xc = (jx + s) & (N - 1);
      fma4(o0, Lq[s], I[buf][0][0][xc]);
      fma4(o0, Hq[s], I[buf][0][1][xc]);
      fma4(o1, Lq[s], I[buf][1][0][xc]);
      fma4(o1, Hq[s], I[buf][1][1][xc]);
    }
    const int jy = r0 + c;
    float4* po = ob + (size_t)(2 * jy) * (2 * N) + t;
    po[0] = o0;
    po[2 * N] = o1;

    if (c < RJ - 1) {
      // ---- Pass1: j-row c+1 (uses window rows c+1..c+4) ----
      p1(c + 1, buf ^ 1);
      // Slide: row c+5 (prefetched, vmcnt-waited here) -> slot (c+1)&3;
      // issue prefetch of row c+6 (stays in flight across the barrier).
      if (c <= RJ - 3) {
        wA[(c + 1) & 3] = nA;
        wB[(c + 1) & 3] = nB;
      }
      if (c <= RJ - 4) ldrow(c + 6, nA, nB);
      LGKM_BARRIER();
    }
  }
}

extern "C" void kernel_launch(void* const* d_in, const int* in_sizes, int n_in,
                              void* d_out, int out_size, void* d_ws,
                              size_t ws_size, hipStream_t stream) {
  const float* x = reinterpret_cast<const float*>(d_in[0]);
  float* out = reinterpret_cast<float*>(d_out);
  const int grid = 64 * (N / RJ);  // 1024 blocks = 4 per CU
  idwt2_sep10_kernel<<<grid, 512, 0, stream>>>(x, out);
}